// Round 3
// baseline (952.930 us; speedup 1.0000x reference)
//
#include <hip/hip_runtime.h>
#include <math.h>

#define D_IN 512
#define F1   16
#define F2   7

// ---------------- in-degree histogram (counting-sort pass 1) ----------------
__global__ __launch_bounds__(256) void hist_kernel(const int* __restrict__ dst,
                                                   int* __restrict__ cnt, int E) {
    int t = blockIdx.x * blockDim.x + threadIdx.x;
    if (t < E) {
        int d = __builtin_nontemporal_load(&dst[t]);
        atomicAdd(&cnt[d], 1);
    }
}

// ---------------- prefix sum (3-kernel block scan) ----------------
__global__ __launch_bounds__(256) void scan1_kernel(const int* __restrict__ cnt,
                                                    int* __restrict__ row_ptr,
                                                    int* __restrict__ blocksums, int n) {
    __shared__ int sm[256];
    int gid = blockIdx.x * 256 + threadIdx.x;
    int v = gid < n ? cnt[gid] : 0;
    sm[threadIdx.x] = v;
    __syncthreads();
    for (int off = 1; off < 256; off <<= 1) {
        int t = threadIdx.x >= off ? sm[threadIdx.x - off] : 0;
        __syncthreads();
        sm[threadIdx.x] += t;
        __syncthreads();
    }
    if (gid < n) row_ptr[gid] = sm[threadIdx.x] - v;  // exclusive within block
    if (threadIdx.x == 255) blocksums[blockIdx.x] = sm[255];
}

__global__ __launch_bounds__(512) void scan2_kernel(int* __restrict__ blocksums, int nb) {
    __shared__ int sm[512];
    int v = ((int)threadIdx.x < nb) ? blocksums[threadIdx.x] : 0;
    sm[threadIdx.x] = v;
    __syncthreads();
    for (int off = 1; off < 512; off <<= 1) {
        int t = threadIdx.x >= off ? sm[threadIdx.x - off] : 0;
        __syncthreads();
        sm[threadIdx.x] += t;
        __syncthreads();
    }
    if ((int)threadIdx.x < nb) blocksums[threadIdx.x] = sm[threadIdx.x] - v;  // exclusive
}

// add block offsets; also init cursor and dinv = rsqrt(deg+1)
__global__ __launch_bounds__(256) void scan3_kernel(int* __restrict__ row_ptr,
                                                    const int* __restrict__ blocksums,
                                                    int* __restrict__ cursor,
                                                    const int* __restrict__ cnt,
                                                    float* __restrict__ dinv, int n) {
    int gid = blockIdx.x * 256 + threadIdx.x;
    if (gid < n) {
        int rp = row_ptr[gid] + blocksums[blockIdx.x];
        row_ptr[gid] = rp;
        cursor[gid] = rp;
        dinv[gid] = rsqrtf((float)cnt[gid] + 1.0f);
    }
}

// ---------------- counting-sort pass 2: scatter src into dst-sorted adj ----------------
// nt loads keep the streaming src/dst out of L2 so adj dirty lines can coalesce.
__global__ __launch_bounds__(256) void scatter_kernel(const int* __restrict__ src,
                                                      const int* __restrict__ dst,
                                                      int* __restrict__ cursor,
                                                      int* __restrict__ adj, int E) {
    int t = blockIdx.x * blockDim.x + threadIdx.x;
    if (t >= E) return;
    int s = __builtin_nontemporal_load(&src[t]);
    int d = __builtin_nontemporal_load(&dst[t]);
    int pos = atomicAdd(&cursor[d], 1);
    adj[pos] = s;
}

// ---------------- layer-1 matmul: h1s = (x @ W1) * dinv[node] ----------------
__global__ __launch_bounds__(256) void mm1_kernel(const float* __restrict__ x,
                                                  const float* __restrict__ W1,
                                                  const float* __restrict__ dinv,
                                                  float* __restrict__ h1s,
                                                  int n, int T) {
    int t = blockIdx.x * blockDim.x + threadIdx.x;
    if (t >= T) return;

    int idx[4];
    bool valid[4];
    const float4* xp[4];
#pragma unroll
    for (int u = 0; u < 4; ++u) {
        int nd = t + u * T;
        valid[u] = nd < n;
        idx[u] = valid[u] ? nd : 0;
        xp[u] = (const float4*)(x + (size_t)idx[u] * D_IN);
    }

    float acc[4][F1];
#pragma unroll
    for (int u = 0; u < 4; ++u)
#pragma unroll
        for (int j = 0; j < F1; ++j) acc[u][j] = 0.0f;

    for (int c = 0; c < D_IN / 4; ++c) {
        float4 av[4];
#pragma unroll
        for (int u = 0; u < 4; ++u) av[u] = xp[u][c];

        const float4* wr = (const float4*)(W1 + (size_t)c * 4 * F1);
#pragma unroll
        for (int kk = 0; kk < 4; ++kk) {
            float4 w[4];
#pragma unroll
            for (int q = 0; q < 4; ++q) w[q] = wr[kk * 4 + q];
            const float* wf = (const float*)w;
#pragma unroll
            for (int u = 0; u < 4; ++u) {
                float xe = ((const float*)&av[u])[kk];
#pragma unroll
                for (int j = 0; j < F1; ++j) acc[u][j] += xe * wf[j];
            }
        }
    }

#pragma unroll
    for (int u = 0; u < 4; ++u) {
        if (!valid[u]) continue;
        float di = dinv[idx[u]];
        float4* outp = (float4*)(h1s + (size_t)idx[u] * F1);
#pragma unroll
        for (int q = 0; q < 4; ++q)
            outp[q] = make_float4(acc[u][4 * q + 0] * di, acc[u][4 * q + 1] * di,
                                  acc[u][4 * q + 2] * di, acc[u][4 * q + 3] * di);
    }
}

// ---- layer-1 gather + fused finalize: acc1 = relu(dinv*(sum + h1s[node]) + b1) ----
// 16 lanes per node, lane j = feature j.
__global__ __launch_bounds__(256) void agg1_kernel(const int* __restrict__ row_ptr,
                                                   const int* __restrict__ row_end,
                                                   const int* __restrict__ adj,
                                                   const float* __restrict__ h,
                                                   const float* __restrict__ dinv,
                                                   const float* __restrict__ b1,
                                                   float* __restrict__ acc, int n) {
    int t = blockIdx.x * 256 + threadIdx.x;
    int node = t >> 4, j = t & 15;
    if (node >= n) return;
    int s = row_ptr[node], e = row_end[node];
    float a0 = 0.0f, a1 = 0.0f;
    int k = s;
    for (; k + 1 < e; k += 2) {
        int s0 = __builtin_nontemporal_load(&adj[k]);
        int s1 = __builtin_nontemporal_load(&adj[k + 1]);
        a0 += h[(size_t)s0 * F1 + j];
        a1 += h[(size_t)s1 * F1 + j];
    }
    if (k < e) a0 += h[(size_t)__builtin_nontemporal_load(&adj[k]) * F1 + j];
    float di = dinv[node];
    float v = di * (a0 + a1 + h[(size_t)node * F1 + j]) + b1[j];
    acc[(size_t)node * F1 + j] = v > 0.0f ? v : 0.0f;
}

// ---------------- layer-2 matmul: h2s = (h @ W2) * dinv, padded stride 8 ----------------
__global__ __launch_bounds__(256) void mm2_kernel(const float* __restrict__ hin,
                                                  const float* __restrict__ W2,
                                                  const float* __restrict__ dinv,
                                                  float* __restrict__ h2s, int n) {
    int t = blockIdx.x * blockDim.x + threadIdx.x;
    if (t >= n) return;
    const float4* hr = (const float4*)(hin + (size_t)t * F1);
    float hv[F1];
#pragma unroll
    for (int q = 0; q < 4; ++q) {
        float4 v = hr[q];
        hv[4 * q + 0] = v.x; hv[4 * q + 1] = v.y;
        hv[4 * q + 2] = v.z; hv[4 * q + 3] = v.w;
    }
    float acc[F2];
#pragma unroll
    for (int j = 0; j < F2; ++j) acc[j] = 0.0f;
#pragma unroll
    for (int k = 0; k < F1; ++k) {
        float xv = hv[k];
#pragma unroll
        for (int j = 0; j < F2; ++j) acc[j] += xv * W2[k * F2 + j];
    }
    float di = dinv[t];
    float* outp = h2s + (size_t)t * 8;
#pragma unroll
    for (int j = 0; j < F2; ++j) outp[j] = acc[j] * di;
    outp[7] = 0.0f;
}

// ---- layer-2 gather + fused bias/self-loop/log_softmax -> out (stride 7) ----
// 8 lanes per node; cross-feature reduction via shuffles within the 8-lane group.
__global__ __launch_bounds__(256) void agg2_kernel(const int* __restrict__ row_ptr,
                                                   const int* __restrict__ row_end,
                                                   const int* __restrict__ adj,
                                                   const float* __restrict__ h,
                                                   const float* __restrict__ dinv,
                                                   const float* __restrict__ b2,
                                                   float* __restrict__ out, int n) {
    int t = blockIdx.x * 256 + threadIdx.x;
    int node = t >> 3, j = t & 7;
    if (node >= n) return;
    int s = row_ptr[node], e = row_end[node];
    float a0 = 0.0f, a1 = 0.0f;
    int k = s;
    for (; k + 1 < e; k += 2) {
        int s0 = __builtin_nontemporal_load(&adj[k]);
        int s1 = __builtin_nontemporal_load(&adj[k + 1]);
        a0 += h[(size_t)s0 * 8 + j];
        a1 += h[(size_t)s1 * 8 + j];
    }
    if (k < e) a0 += h[(size_t)__builtin_nontemporal_load(&adj[k]) * 8 + j];
    float di = dinv[node];
    float bj = j < F2 ? b2[j] : 0.0f;
    float v = di * (a0 + a1 + h[(size_t)node * 8 + j]) + bj;
    if (j >= F2) v = -INFINITY;   // pad lane: never the max, exp()=0
    // 8-lane max reduce
    float m = v;
#pragma unroll
    for (int w = 1; w < 8; w <<= 1) m = fmaxf(m, __shfl_xor(m, w, 8));
    // 8-lane sum of exp(v-m)
    float ex = (j < F2) ? expf(v - m) : 0.0f;
    float sum = ex;
#pragma unroll
    for (int w = 1; w < 8; w <<= 1) sum += __shfl_xor(sum, w, 8);
    float lse = m + logf(sum);
    if (j < F2) out[(size_t)node * F2 + j] = v - lse;
}

extern "C" void kernel_launch(void* const* d_in, const int* in_sizes, int n_in,
                              void* d_out, int out_size, void* d_ws, size_t ws_size,
                              hipStream_t stream) {
    const float* x  = (const float*)d_in[0];
    const int*   ei = (const int*)d_in[1];
    const float* W1 = (const float*)d_in[2];
    const float* b1 = (const float*)d_in[3];
    const float* W2 = (const float*)d_in[4];
    const float* b2 = (const float*)d_in[5];

    int n = in_sizes[0] / D_IN;
    int E = in_sizes[1] / 2;
    const int* src = ei;
    const int* dst = ei + E;

    // workspace layout (4-byte elements)
    char* ws = (char*)d_ws;
    size_t o = 0;
    int*   cnt       = (int*)(ws + o);  o += (size_t)n * 4;
    int*   row_ptr   = (int*)(ws + o);  o += (size_t)n * 4;
    int*   cursor    = (int*)(ws + o);  o += (size_t)n * 4;   // becomes row_end after scatter
    float* dinv      = (float*)(ws + o); o += (size_t)n * 4;
    int*   blocksums = (int*)(ws + o);  o += 512 * 4;
    int*   adj       = (int*)(ws + o);  o += (size_t)E * 4;
    float* h1s       = (float*)(ws + o); o += (size_t)n * F1 * 4;  // reused as h2s (stride 8)
    float* acc1      = (float*)(ws + o); o += (size_t)n * F1 * 4;  // relu'd layer-1 output
    float* h2s = h1s;  // mm2 reads acc1, writes h2s (= h1s, dead after agg1) — sequential stream, safe

    float* out = (float*)d_out;

    const int B = 256;
    int gE = (E + B - 1) / B;
    int gN = (n + B - 1) / B;
    int nb = (n + 255) / 256;

    hipMemsetAsync(cnt, 0, (size_t)n * sizeof(int), stream);

    hist_kernel<<<gE, B, 0, stream>>>(dst, cnt, E);
    scan1_kernel<<<nb, 256, 0, stream>>>(cnt, row_ptr, blocksums, n);
    scan2_kernel<<<1, 512, 0, stream>>>(blocksums, nb);
    scan3_kernel<<<nb, 256, 0, stream>>>(row_ptr, blocksums, cursor, cnt, dinv, n);

    scatter_kernel<<<gE, B, 0, stream>>>(src, dst, cursor, adj, E);

    int T = (n + 3) / 4;
    mm1_kernel<<<(T + B - 1) / B, B, 0, stream>>>(x, W1, dinv, h1s, n, T);

    agg1_kernel<<<((size_t)n * F1 + B - 1) / B, B, 0, stream>>>(row_ptr, cursor, adj, h1s, dinv, b1, acc1, n);

    mm2_kernel<<<gN, B, 0, stream>>>(acc1, W2, dinv, h2s, n);

    agg2_kernel<<<((size_t)n * 8 + B - 1) / B, B, 0, stream>>>(row_ptr, cursor, adj, h2s, dinv, b2, out, n);
}

// Round 4
// 587.254 us; speedup vs baseline: 1.6227x; 1.6227x over previous
//
#include <hip/hip_runtime.h>
#include <math.h>

#define D_IN 512
#define F1   16
#define F2   7

#define BKT_SHIFT 8                 // 256 nodes per bucket
#define PK_SHIFT  18                // packed word: src | (dst&255)<<18  (needs n <= 2^18)
#define PK_MASK   ((1u << PK_SHIFT) - 1u)
#define A_CHUNK   8192              // edges per workgroup in binning passes
#define B_CAP     16384             // LDS staging capacity in CSR pass (2x mean bucket size)

// ---- pass A1: per-bucket edge histogram (LDS-aggregated) ----
__global__ __launch_bounds__(256) void binhist_kernel(const int* __restrict__ dst,
                                                      int* __restrict__ bucket_cnt,
                                                      int E, int NB) {
    __shared__ int lh[512];
    for (int i = threadIdx.x; i < 512; i += 256) lh[i] = 0;
    __syncthreads();
    int base = blockIdx.x * A_CHUNK;
#pragma unroll
    for (int i = 0; i < A_CHUNK / 256; ++i) {
        int t = base + i * 256 + threadIdx.x;
        if (t < E) {
            int d = __builtin_nontemporal_load(&dst[t]);
            atomicAdd(&lh[d >> BKT_SHIFT], 1);
        }
    }
    __syncthreads();
    for (int i = threadIdx.x; i < NB; i += 256) {
        int v = lh[i];
        if (v) atomicAdd(&bucket_cnt[i], v);
    }
}

// ---- bucket scan: exclusive scan of bucket_cnt -> bucket_base, init bucket_cursor ----
__global__ __launch_bounds__(512) void bucketscan_kernel(const int* __restrict__ bucket_cnt,
                                                         int* __restrict__ bucket_base,
                                                         int* __restrict__ bucket_cursor,
                                                         int NB, int E) {
    __shared__ int sm[512];
    int tid = threadIdx.x;
    int v = (tid < NB) ? bucket_cnt[tid] : 0;
    sm[tid] = v;
    __syncthreads();
    for (int off = 1; off < 512; off <<= 1) {
        int t = (tid >= off) ? sm[tid - off] : 0;
        __syncthreads();
        sm[tid] += t;
        __syncthreads();
    }
    if (tid < NB) {
        int ex = sm[tid] - v;
        bucket_base[tid] = ex;
        bucket_cursor[tid] = ex;
    }
    if (tid == 0) bucket_base[NB] = E;
}

// ---- pass A2: bin edges into bucket regions with segment-contiguous writes ----
__global__ __launch_bounds__(256) void bin_kernel(const int* __restrict__ src,
                                                  const int* __restrict__ dst,
                                                  int* __restrict__ bucket_cursor,
                                                  unsigned int* __restrict__ binned,
                                                  int E, int NB) {
    __shared__ int lh[512];       // local bucket hist
    __shared__ int lbase[512];    // local exclusive scan
    __shared__ int lcur[512];     // local alloc cursor
    __shared__ int sdelta[512];   // global_seg_base - lbase
    __shared__ int sA[512], sB[512];
    __shared__ unsigned int rbuf[A_CHUNK];
    __shared__ int rdelta[A_CHUNK];
    int tid = threadIdx.x;
    for (int i = tid; i < 512; i += 256) lh[i] = 0;
    __syncthreads();

    int base = blockIdx.x * A_CHUNK;
    int dcache[A_CHUNK / 256];
    int scache[A_CHUNK / 256];
#pragma unroll
    for (int i = 0; i < A_CHUNK / 256; ++i) {
        int t = base + i * 256 + tid;
        int d = -1, s = 0;
        if (t < E) {
            d = __builtin_nontemporal_load(&dst[t]);
            s = __builtin_nontemporal_load(&src[t]);
            atomicAdd(&lh[d >> BKT_SHIFT], 1);
        }
        dcache[i] = d;
        scache[i] = s;
    }
    __syncthreads();

    // scan lh (512 entries, ping-pong Hillis-Steele) -> inclusive in psrc
    for (int i = tid; i < 512; i += 256) sA[i] = lh[i];
    __syncthreads();
    int* psrc = sA; int* pdst = sB;
    for (int off = 1; off < 512; off <<= 1) {
        for (int i = tid; i < 512; i += 256)
            pdst[i] = psrc[i] + ((i >= off) ? psrc[i - off] : 0);
        __syncthreads();
        int* tmp = psrc; psrc = pdst; pdst = tmp;
    }
    for (int i = tid; i < 512; i += 256) {
        int ex = psrc[i] - lh[i];
        lbase[i] = ex;
        lcur[i] = ex;
    }
    __syncthreads();

    // reserve one global segment per bucket for this chunk
    for (int b = tid; b < NB; b += 256) {
        int c = lh[b];
        int g = c ? atomicAdd(&bucket_cursor[b], c) : 0;
        sdelta[b] = g - lbase[b];
    }
    __syncthreads();

    // local reorder into rbuf
#pragma unroll
    for (int i = 0; i < A_CHUNK / 256; ++i) {
        int d = dcache[i];
        if (d >= 0) {
            int b = d >> BKT_SHIFT;
            int p = atomicAdd(&lcur[b], 1);
            rbuf[p] = (unsigned int)scache[i] | ((unsigned int)(d & 255) << PK_SHIFT);
            rdelta[p] = sdelta[b];
        }
    }
    __syncthreads();

    // write out: positions p within a segment map to consecutive global addresses
    int total = min(A_CHUNK, E - base);
    for (int p = tid; p < total; p += 256)
        binned[rdelta[p] + p] = rbuf[p];
}

// ---- pass B: per-bucket local counting sort -> adj, row_ptr/row_end/dinv ----
__global__ __launch_bounds__(256) void csr_kernel(const unsigned int* __restrict__ binned,
                                                  const int* __restrict__ bucket_base,
                                                  int* __restrict__ row_ptr,
                                                  int* __restrict__ row_end,
                                                  float* __restrict__ dinv,
                                                  int* __restrict__ adj, int n) {
    __shared__ int lh[256], lscan[256], lcur[256];
    __shared__ unsigned int rbuf[B_CAP];
    int b = blockIdx.x;
    int tid = threadIdx.x;
    int gbase = bucket_base[b];
    int gend  = bucket_base[b + 1];
    int m = gend - gbase;
    lh[tid] = 0;
    __syncthreads();
    // hist + LDS stage (nt loads: streaming, don't evict adj dirty lines)
    for (int i = tid; i < m; i += 256) {
        unsigned int w = __builtin_nontemporal_load(&binned[gbase + i]);
        if (i < B_CAP) rbuf[i] = w;
        atomicAdd(&lh[w >> PK_SHIFT], 1);
    }
    __syncthreads();
    // 256-entry Hillis-Steele scan
    int v = lh[tid];
    lscan[tid] = v;
    __syncthreads();
    for (int off = 1; off < 256; off <<= 1) {
        int t = (tid >= off) ? lscan[tid - off] : 0;
        __syncthreads();
        lscan[tid] += t;
        __syncthreads();
    }
    int ex = lscan[tid] - v;  // exclusive
    int node = (b << BKT_SHIFT) + tid;
    if (node < n) {
        row_ptr[node] = gbase + ex;
        row_end[node] = gbase + ex + v;
        dinv[node] = rsqrtf((float)v + 1.0f);
    }
    lcur[tid] = ex;
    __syncthreads();
    // scatter into this bucket's private 32KB adj window (L2 merges the fills)
    for (int i = tid; i < m; i += 256) {
        unsigned int w = (i < B_CAP) ? rbuf[i] : binned[gbase + i];
        int d = (int)(w >> PK_SHIFT);
        int s = (int)(w & PK_MASK);
        int p = atomicAdd(&lcur[d], 1);
        adj[gbase + p] = s;
    }
}

// ---------------- layer-1 matmul: h1s = (x @ W1) * dinv[node] ----------------
__global__ __launch_bounds__(256) void mm1_kernel(const float* __restrict__ x,
                                                  const float* __restrict__ W1,
                                                  const float* __restrict__ dinv,
                                                  float* __restrict__ h1s,
                                                  int n, int T) {
    int t = blockIdx.x * blockDim.x + threadIdx.x;
    if (t >= T) return;

    int idx[4];
    bool valid[4];
    const float4* xp[4];
#pragma unroll
    for (int u = 0; u < 4; ++u) {
        int nd = t + u * T;
        valid[u] = nd < n;
        idx[u] = valid[u] ? nd : 0;
        xp[u] = (const float4*)(x + (size_t)idx[u] * D_IN);
    }

    float acc[4][F1];
#pragma unroll
    for (int u = 0; u < 4; ++u)
#pragma unroll
        for (int j = 0; j < F1; ++j) acc[u][j] = 0.0f;

    for (int c = 0; c < D_IN / 4; ++c) {
        float4 av[4];
#pragma unroll
        for (int u = 0; u < 4; ++u) av[u] = xp[u][c];

        const float4* wr = (const float4*)(W1 + (size_t)c * 4 * F1);
#pragma unroll
        for (int kk = 0; kk < 4; ++kk) {
            float4 w[4];
#pragma unroll
            for (int q = 0; q < 4; ++q) w[q] = wr[kk * 4 + q];
            const float* wf = (const float*)w;
#pragma unroll
            for (int u = 0; u < 4; ++u) {
                float xe = ((const float*)&av[u])[kk];
#pragma unroll
                for (int j = 0; j < F1; ++j) acc[u][j] += xe * wf[j];
            }
        }
    }

#pragma unroll
    for (int u = 0; u < 4; ++u) {
        if (!valid[u]) continue;
        float di = dinv[idx[u]];
        float4* outp = (float4*)(h1s + (size_t)idx[u] * F1);
#pragma unroll
        for (int q = 0; q < 4; ++q)
            outp[q] = make_float4(acc[u][4 * q + 0] * di, acc[u][4 * q + 1] * di,
                                  acc[u][4 * q + 2] * di, acc[u][4 * q + 3] * di);
    }
}

// ---- layer-1 gather + fused finalize: acc1 = relu(dinv*(sum + h1s[node]) + b1) ----
__global__ __launch_bounds__(256) void agg1_kernel(const int* __restrict__ row_ptr,
                                                   const int* __restrict__ row_end,
                                                   const int* __restrict__ adj,
                                                   const float* __restrict__ h,
                                                   const float* __restrict__ dinv,
                                                   const float* __restrict__ b1,
                                                   float* __restrict__ acc, int n) {
    int t = blockIdx.x * 256 + threadIdx.x;
    int node = t >> 4, j = t & 15;
    if (node >= n) return;
    int s = row_ptr[node], e = row_end[node];
    float a0 = 0.0f, a1 = 0.0f;
    int k = s;
    for (; k + 1 < e; k += 2) {
        int s0 = adj[k], s1 = adj[k + 1];
        a0 += h[(size_t)s0 * F1 + j];
        a1 += h[(size_t)s1 * F1 + j];
    }
    if (k < e) a0 += h[(size_t)adj[k] * F1 + j];
    float di = dinv[node];
    float v = di * (a0 + a1 + h[(size_t)node * F1 + j]) + b1[j];
    acc[(size_t)node * F1 + j] = v > 0.0f ? v : 0.0f;
}

// ---------------- layer-2 matmul: h2s = (h @ W2) * dinv, padded stride 8 ----------------
__global__ __launch_bounds__(256) void mm2_kernel(const float* __restrict__ hin,
                                                  const float* __restrict__ W2,
                                                  const float* __restrict__ dinv,
                                                  float* __restrict__ h2s, int n) {
    int t = blockIdx.x * blockDim.x + threadIdx.x;
    if (t >= n) return;
    const float4* hr = (const float4*)(hin + (size_t)t * F1);
    float hv[F1];
#pragma unroll
    for (int q = 0; q < 4; ++q) {
        float4 v = hr[q];
        hv[4 * q + 0] = v.x; hv[4 * q + 1] = v.y;
        hv[4 * q + 2] = v.z; hv[4 * q + 3] = v.w;
    }
    float acc[F2];
#pragma unroll
    for (int j = 0; j < F2; ++j) acc[j] = 0.0f;
#pragma unroll
    for (int k = 0; k < F1; ++k) {
        float xv = hv[k];
#pragma unroll
        for (int j = 0; j < F2; ++j) acc[j] += xv * W2[k * F2 + j];
    }
    float di = dinv[t];
    float* outp = h2s + (size_t)t * 8;
#pragma unroll
    for (int j = 0; j < F2; ++j) outp[j] = acc[j] * di;
    outp[7] = 0.0f;
}

// ---- layer-2 gather + fused bias/self-loop/log_softmax -> out (stride 7) ----
__global__ __launch_bounds__(256) void agg2_kernel(const int* __restrict__ row_ptr,
                                                   const int* __restrict__ row_end,
                                                   const int* __restrict__ adj,
                                                   const float* __restrict__ h,
                                                   const float* __restrict__ dinv,
                                                   const float* __restrict__ b2,
                                                   float* __restrict__ out, int n) {
    int t = blockIdx.x * 256 + threadIdx.x;
    int node = t >> 3, j = t & 7;
    if (node >= n) return;
    int s = row_ptr[node], e = row_end[node];
    float a0 = 0.0f, a1 = 0.0f;
    int k = s;
    for (; k + 1 < e; k += 2) {
        int s0 = adj[k], s1 = adj[k + 1];
        a0 += h[(size_t)s0 * 8 + j];
        a1 += h[(size_t)s1 * 8 + j];
    }
    if (k < e) a0 += h[(size_t)adj[k] * 8 + j];
    float di = dinv[node];
    float bj = j < F2 ? b2[j] : 0.0f;
    float v = di * (a0 + a1 + h[(size_t)node * 8 + j]) + bj;
    if (j >= F2) v = -INFINITY;   // pad lane: never the max, exp()=0
    float m = v;
#pragma unroll
    for (int w = 1; w < 8; w <<= 1) m = fmaxf(m, __shfl_xor(m, w, 8));
    float ex = (j < F2) ? expf(v - m) : 0.0f;
    float sum = ex;
#pragma unroll
    for (int w = 1; w < 8; w <<= 1) sum += __shfl_xor(sum, w, 8);
    float lse = m + logf(sum);
    if (j < F2) out[(size_t)node * F2 + j] = v - lse;
}

extern "C" void kernel_launch(void* const* d_in, const int* in_sizes, int n_in,
                              void* d_out, int out_size, void* d_ws, size_t ws_size,
                              hipStream_t stream) {
    const float* x  = (const float*)d_in[0];
    const int*   ei = (const int*)d_in[1];
    const float* W1 = (const float*)d_in[2];
    const float* b1 = (const float*)d_in[3];
    const float* W2 = (const float*)d_in[4];
    const float* b2 = (const float*)d_in[5];

    int n = in_sizes[0] / D_IN;
    int E = in_sizes[1] / 2;
    const int* src = ei;
    const int* dst = ei + E;
    int NB = (n + 255) >> BKT_SHIFT;   // buckets (<=512 for n<=131072)

    // workspace layout (4-byte elements); binned aliases h1s/acc1 (dead before mm1)
    char* ws = (char*)d_ws;
    size_t o = 0;
    int* bucket_cnt    = (int*)(ws + o); o += 512 * 4;
    int* bucket_base   = (int*)(ws + o); o += 516 * 4;
    int* bucket_cursor = (int*)(ws + o); o += 512 * 4;
    int*   row_ptr = (int*)(ws + o);   o += (size_t)n * 4;
    int*   row_end = (int*)(ws + o);   o += (size_t)n * 4;
    float* dinv    = (float*)(ws + o); o += (size_t)n * 4;
    int*   adj     = (int*)(ws + o);   o += (size_t)E * 4;
    size_t uni = (size_t)E > (size_t)n * 32 ? (size_t)E : (size_t)n * 32;
    unsigned int* binned = (unsigned int*)(ws + o);
    float* h1s  = (float*)(ws + o);                    // overwrites binned after csr pass
    float* acc1 = (float*)(ws + o) + (size_t)n * F1;
    o += uni * 4;
    float* h2s = h1s;  // mm2 reads acc1, writes h2s (h1s dead after agg1)
    float* out = (float*)d_out;

    const int B = 256;
    int GA = (E + A_CHUNK - 1) / A_CHUNK;
    int gN = (n + B - 1) / B;

    hipMemsetAsync(bucket_cnt, 0, 512 * sizeof(int), stream);

    binhist_kernel<<<GA, B, 0, stream>>>(dst, bucket_cnt, E, NB);
    bucketscan_kernel<<<1, 512, 0, stream>>>(bucket_cnt, bucket_base, bucket_cursor, NB, E);
    bin_kernel<<<GA, B, 0, stream>>>(src, dst, bucket_cursor, binned, E, NB);
    csr_kernel<<<NB, B, 0, stream>>>(binned, bucket_base, row_ptr, row_end, dinv, adj, n);

    int T = (n + 3) / 4;
    mm1_kernel<<<(T + B - 1) / B, B, 0, stream>>>(x, W1, dinv, h1s, n, T);

    agg1_kernel<<<((size_t)n * F1 + B - 1) / B, B, 0, stream>>>(row_ptr, row_end, adj, h1s, dinv, b1, acc1, n);

    mm2_kernel<<<gN, B, 0, stream>>>(acc1, W2, dinv, h2s, n);

    agg2_kernel<<<((size_t)n * 8 + B - 1) / B, B, 0, stream>>>(row_ptr, row_end, adj, h2s, dinv, b2, out, n);
}

// Round 5
// 579.887 us; speedup vs baseline: 1.6433x; 1.0127x over previous
//
#include <hip/hip_runtime.h>
#include <math.h>

#define D_IN 512
#define F1   16
#define F2   7

#define BKT_SHIFT 8                 // 256 nodes per bucket
#define PK_SHIFT  18                // packed word: src | (dst&255)<<18  (needs n <= 2^18)
#define PK_MASK   ((1u << PK_SHIFT) - 1u)
#define A_CHUNK   8192              // edges per workgroup in binning passes
#define B_CAP     16384             // LDS staging capacity in CSR pass (2x mean bucket size)
#define NT        64                // nodes per block in mm1

// ---- pass A1: per-bucket edge histogram (LDS-aggregated) ----
__global__ __launch_bounds__(256) void binhist_kernel(const int* __restrict__ dst,
                                                      int* __restrict__ bucket_cnt,
                                                      int E, int NB) {
    __shared__ int lh[512];
    for (int i = threadIdx.x; i < 512; i += 256) lh[i] = 0;
    __syncthreads();
    int base = blockIdx.x * A_CHUNK;
#pragma unroll
    for (int i = 0; i < A_CHUNK / 256; ++i) {
        int t = base + i * 256 + threadIdx.x;
        if (t < E) {
            int d = __builtin_nontemporal_load(&dst[t]);
            atomicAdd(&lh[d >> BKT_SHIFT], 1);
        }
    }
    __syncthreads();
    for (int i = threadIdx.x; i < NB; i += 256) {
        int v = lh[i];
        if (v) atomicAdd(&bucket_cnt[i], v);
    }
}

// ---- bucket scan: exclusive scan of bucket_cnt -> bucket_base, init bucket_cursor ----
__global__ __launch_bounds__(512) void bucketscan_kernel(const int* __restrict__ bucket_cnt,
                                                         int* __restrict__ bucket_base,
                                                         int* __restrict__ bucket_cursor,
                                                         int NB, int E) {
    __shared__ int sm[512];
    int tid = threadIdx.x;
    int v = (tid < NB) ? bucket_cnt[tid] : 0;
    sm[tid] = v;
    __syncthreads();
    for (int off = 1; off < 512; off <<= 1) {
        int t = (tid >= off) ? sm[tid - off] : 0;
        __syncthreads();
        sm[tid] += t;
        __syncthreads();
    }
    if (tid < NB) {
        int ex = sm[tid] - v;
        bucket_base[tid] = ex;
        bucket_cursor[tid] = ex;
    }
    if (tid == 0) bucket_base[NB] = E;
}

// ---- pass A2: bin edges into bucket regions with segment-contiguous writes ----
__global__ __launch_bounds__(256) void bin_kernel(const int* __restrict__ src,
                                                  const int* __restrict__ dst,
                                                  int* __restrict__ bucket_cursor,
                                                  unsigned int* __restrict__ binned,
                                                  int E, int NB) {
    __shared__ int lh[512];       // local bucket hist
    __shared__ int lbase[512];    // local exclusive scan
    __shared__ int lcur[512];     // local alloc cursor
    __shared__ int sdelta[512];   // global_seg_base - lbase
    __shared__ int sA[512], sB[512];
    __shared__ unsigned int rbuf[A_CHUNK];
    __shared__ int rdelta[A_CHUNK];
    int tid = threadIdx.x;
    for (int i = tid; i < 512; i += 256) lh[i] = 0;
    __syncthreads();

    int base = blockIdx.x * A_CHUNK;
    int dcache[A_CHUNK / 256];
    int scache[A_CHUNK / 256];
#pragma unroll
    for (int i = 0; i < A_CHUNK / 256; ++i) {
        int t = base + i * 256 + tid;
        int d = -1, s = 0;
        if (t < E) {
            d = __builtin_nontemporal_load(&dst[t]);
            s = __builtin_nontemporal_load(&src[t]);
            atomicAdd(&lh[d >> BKT_SHIFT], 1);
        }
        dcache[i] = d;
        scache[i] = s;
    }
    __syncthreads();

    // scan lh (512 entries, ping-pong Hillis-Steele) -> inclusive in psrc
    for (int i = tid; i < 512; i += 256) sA[i] = lh[i];
    __syncthreads();
    int* psrc = sA; int* pdst = sB;
    for (int off = 1; off < 512; off <<= 1) {
        for (int i = tid; i < 512; i += 256)
            pdst[i] = psrc[i] + ((i >= off) ? psrc[i - off] : 0);
        __syncthreads();
        int* tmp = psrc; psrc = pdst; pdst = tmp;
    }
    for (int i = tid; i < 512; i += 256) {
        int ex = psrc[i] - lh[i];
        lbase[i] = ex;
        lcur[i] = ex;
    }
    __syncthreads();

    // reserve one global segment per bucket for this chunk
    for (int b = tid; b < NB; b += 256) {
        int c = lh[b];
        int g = c ? atomicAdd(&bucket_cursor[b], c) : 0;
        sdelta[b] = g - lbase[b];
    }
    __syncthreads();

    // local reorder into rbuf
#pragma unroll
    for (int i = 0; i < A_CHUNK / 256; ++i) {
        int d = dcache[i];
        if (d >= 0) {
            int b = d >> BKT_SHIFT;
            int p = atomicAdd(&lcur[b], 1);
            rbuf[p] = (unsigned int)scache[i] | ((unsigned int)(d & 255) << PK_SHIFT);
            rdelta[p] = sdelta[b];
        }
    }
    __syncthreads();

    // write out: positions p within a segment map to consecutive global addresses
    int total = min(A_CHUNK, E - base);
    for (int p = tid; p < total; p += 256)
        binned[rdelta[p] + p] = rbuf[p];
}

// ---- pass B: per-bucket local counting sort -> adj, row_ptr/row_end/dinv ----
__global__ __launch_bounds__(256) void csr_kernel(const unsigned int* __restrict__ binned,
                                                  const int* __restrict__ bucket_base,
                                                  int* __restrict__ row_ptr,
                                                  int* __restrict__ row_end,
                                                  float* __restrict__ dinv,
                                                  int* __restrict__ adj, int n) {
    __shared__ int lh[256], lscan[256], lcur[256];
    __shared__ unsigned int rbuf[B_CAP];
    int b = blockIdx.x;
    int tid = threadIdx.x;
    int gbase = bucket_base[b];
    int gend  = bucket_base[b + 1];
    int m = gend - gbase;
    lh[tid] = 0;
    __syncthreads();
    // hist + LDS stage (nt loads: streaming, don't evict adj dirty lines)
    for (int i = tid; i < m; i += 256) {
        unsigned int w = __builtin_nontemporal_load(&binned[gbase + i]);
        if (i < B_CAP) rbuf[i] = w;
        atomicAdd(&lh[w >> PK_SHIFT], 1);
    }
    __syncthreads();
    // 256-entry Hillis-Steele scan
    int v = lh[tid];
    lscan[tid] = v;
    __syncthreads();
    for (int off = 1; off < 256; off <<= 1) {
        int t = (tid >= off) ? lscan[tid - off] : 0;
        __syncthreads();
        lscan[tid] += t;
        __syncthreads();
    }
    int ex = lscan[tid] - v;  // exclusive
    int node = (b << BKT_SHIFT) + tid;
    if (node < n) {
        row_ptr[node] = gbase + ex;
        row_end[node] = gbase + ex + v;
        dinv[node] = rsqrtf((float)v + 1.0f);
    }
    lcur[tid] = ex;
    __syncthreads();
    // scatter into this bucket's private 32KB adj window (L2 merges the fills)
    for (int i = tid; i < m; i += 256) {
        unsigned int w = (i < B_CAP) ? rbuf[i] : binned[gbase + i];
        int d = (int)(w >> PK_SHIFT);
        int s = (int)(w & PK_MASK);
        int p = atomicAdd(&lcur[d], 1);
        adj[gbase + p] = s;
    }
}

// ---- layer-1 matmul: h1s = (x @ W1) * dinv[node], K-split cooperative tile ----
// Block = 256 threads = 4 waves; wave w handles K-chunk [128w,128w+128); lane = node.
// Partials reduced through LDS; grid = n/64 blocks for full-chip occupancy.
__global__ __launch_bounds__(256) void mm1_kernel(const float* __restrict__ x,
                                                  const float* __restrict__ W1,
                                                  const float* __restrict__ dinv,
                                                  float* __restrict__ h1s, int n) {
    __shared__ float red[4][NT][F1];   // 16 KB
    int tid = threadIdx.x;
    int w = tid >> 6;        // wave id -> K chunk
    int l = tid & 63;        // lane -> node within tile
    int node = blockIdx.x * NT + l;
    int nd = node < n ? node : 0;

    const float4* xp = (const float4*)(x + (size_t)nd * D_IN + (size_t)w * 128);
    float acc[F1];
#pragma unroll
    for (int j = 0; j < F1; ++j) acc[j] = 0.0f;

    for (int c = 0; c < 32; ++c) {       // 32 float4 = 128 floats of K
        float4 xv = xp[c];
        const float4* wr = (const float4*)(W1 + (size_t)(w * 128 + c * 4) * F1);
#pragma unroll
        for (int kk = 0; kk < 4; ++kk) {
            float xe = ((const float*)&xv)[kk];
            float4 w0 = wr[kk * 4 + 0], w1 = wr[kk * 4 + 1];
            float4 w2 = wr[kk * 4 + 2], w3 = wr[kk * 4 + 3];
            acc[ 0] += xe * w0.x; acc[ 1] += xe * w0.y; acc[ 2] += xe * w0.z; acc[ 3] += xe * w0.w;
            acc[ 4] += xe * w1.x; acc[ 5] += xe * w1.y; acc[ 6] += xe * w1.z; acc[ 7] += xe * w1.w;
            acc[ 8] += xe * w2.x; acc[ 9] += xe * w2.y; acc[10] += xe * w2.z; acc[11] += xe * w2.w;
            acc[12] += xe * w3.x; acc[13] += xe * w3.y; acc[14] += xe * w3.z; acc[15] += xe * w3.w;
        }
    }

#pragma unroll
    for (int q = 0; q < 4; ++q)
        ((float4*)&red[w][l][0])[q] = make_float4(acc[4 * q + 0], acc[4 * q + 1],
                                                  acc[4 * q + 2], acc[4 * q + 3]);
    __syncthreads();

    // reduce 4 partials: thread t -> node nl = t>>2, feature group (t&3)*4
    int nl = tid >> 2, jg = (tid & 3) * 4;
    int onode = blockIdx.x * NT + nl;
    if (onode < n) {
        float4 s = make_float4(0.f, 0.f, 0.f, 0.f);
#pragma unroll
        for (int ww = 0; ww < 4; ++ww) {
            float4 p = *((const float4*)&red[ww][nl][jg]);
            s.x += p.x; s.y += p.y; s.z += p.z; s.w += p.w;
        }
        float di = dinv[onode];
        s.x *= di; s.y *= di; s.z *= di; s.w *= di;
        *((float4*)(h1s + (size_t)onode * F1 + jg)) = s;
    }
}

// ---- layer-1 gather + fused finalize: acc1 = relu(dinv*(sum + h1s[node]) + b1) ----
__global__ __launch_bounds__(256) void agg1_kernel(const int* __restrict__ row_ptr,
                                                   const int* __restrict__ row_end,
                                                   const int* __restrict__ adj,
                                                   const float* __restrict__ h,
                                                   const float* __restrict__ dinv,
                                                   const float* __restrict__ b1,
                                                   float* __restrict__ acc, int n) {
    int t = blockIdx.x * 256 + threadIdx.x;
    int node = t >> 4, j = t & 15;
    if (node >= n) return;
    int s = row_ptr[node], e = row_end[node];
    float a0 = 0.0f, a1 = 0.0f;
    int k = s;
    for (; k + 1 < e; k += 2) {
        int s0 = adj[k], s1 = adj[k + 1];
        a0 += h[(size_t)s0 * F1 + j];
        a1 += h[(size_t)s1 * F1 + j];
    }
    if (k < e) a0 += h[(size_t)adj[k] * F1 + j];
    float di = dinv[node];
    float v = di * (a0 + a1 + h[(size_t)node * F1 + j]) + b1[j];
    acc[(size_t)node * F1 + j] = v > 0.0f ? v : 0.0f;
}

// ---------------- layer-2 matmul: h2s = (h @ W2) * dinv, padded stride 8 ----------------
__global__ __launch_bounds__(256) void mm2_kernel(const float* __restrict__ hin,
                                                  const float* __restrict__ W2,
                                                  const float* __restrict__ dinv,
                                                  float* __restrict__ h2s, int n) {
    int t = blockIdx.x * blockDim.x + threadIdx.x;
    if (t >= n) return;
    const float4* hr = (const float4*)(hin + (size_t)t * F1);
    float hv[F1];
#pragma unroll
    for (int q = 0; q < 4; ++q) {
        float4 v = hr[q];
        hv[4 * q + 0] = v.x; hv[4 * q + 1] = v.y;
        hv[4 * q + 2] = v.z; hv[4 * q + 3] = v.w;
    }
    float acc[F2];
#pragma unroll
    for (int j = 0; j < F2; ++j) acc[j] = 0.0f;
#pragma unroll
    for (int k = 0; k < F1; ++k) {
        float xv = hv[k];
#pragma unroll
        for (int j = 0; j < F2; ++j) acc[j] += xv * W2[k * F2 + j];
    }
    float di = dinv[t];
    float* outp = h2s + (size_t)t * 8;
#pragma unroll
    for (int j = 0; j < F2; ++j) outp[j] = acc[j] * di;
    outp[7] = 0.0f;
}

// ---- layer-2 gather + fused bias/self-loop/log_softmax -> out (stride 7) ----
__global__ __launch_bounds__(256) void agg2_kernel(const int* __restrict__ row_ptr,
                                                   const int* __restrict__ row_end,
                                                   const int* __restrict__ adj,
                                                   const float* __restrict__ h,
                                                   const float* __restrict__ dinv,
                                                   const float* __restrict__ b2,
                                                   float* __restrict__ out, int n) {
    int t = blockIdx.x * 256 + threadIdx.x;
    int node = t >> 3, j = t & 7;
    if (node >= n) return;
    int s = row_ptr[node], e = row_end[node];
    float a0 = 0.0f, a1 = 0.0f;
    int k = s;
    for (; k + 1 < e; k += 2) {
        int s0 = adj[k], s1 = adj[k + 1];
        a0 += h[(size_t)s0 * 8 + j];
        a1 += h[(size_t)s1 * 8 + j];
    }
    if (k < e) a0 += h[(size_t)adj[k] * 8 + j];
    float di = dinv[node];
    float bj = j < F2 ? b2[j] : 0.0f;
    float v = di * (a0 + a1 + h[(size_t)node * 8 + j]) + bj;
    if (j >= F2) v = -INFINITY;   // pad lane: never the max, exp()=0
    float m = v;
#pragma unroll
    for (int w = 1; w < 8; w <<= 1) m = fmaxf(m, __shfl_xor(m, w, 8));
    float ex = (j < F2) ? expf(v - m) : 0.0f;
    float sum = ex;
#pragma unroll
    for (int w = 1; w < 8; w <<= 1) sum += __shfl_xor(sum, w, 8);
    float lse = m + logf(sum);
    if (j < F2) out[(size_t)node * F2 + j] = v - lse;
}

extern "C" void kernel_launch(void* const* d_in, const int* in_sizes, int n_in,
                              void* d_out, int out_size, void* d_ws, size_t ws_size,
                              hipStream_t stream) {
    const float* x  = (const float*)d_in[0];
    const int*   ei = (const int*)d_in[1];
    const float* W1 = (const float*)d_in[2];
    const float* b1 = (const float*)d_in[3];
    const float* W2 = (const float*)d_in[4];
    const float* b2 = (const float*)d_in[5];

    int n = in_sizes[0] / D_IN;
    int E = in_sizes[1] / 2;
    const int* src = ei;
    const int* dst = ei + E;
    int NB = (n + 255) >> BKT_SHIFT;   // buckets (<=512 for n<=131072)

    // workspace layout (4-byte elements); binned aliases h1s/acc1 (dead before mm1)
    char* ws = (char*)d_ws;
    size_t o = 0;
    int* bucket_cnt    = (int*)(ws + o); o += 512 * 4;
    int* bucket_base   = (int*)(ws + o); o += 516 * 4;
    int* bucket_cursor = (int*)(ws + o); o += 512 * 4;
    int*   row_ptr = (int*)(ws + o);   o += (size_t)n * 4;
    int*   row_end = (int*)(ws + o);   o += (size_t)n * 4;
    float* dinv    = (float*)(ws + o); o += (size_t)n * 4;
    int*   adj     = (int*)(ws + o);   o += (size_t)E * 4;
    size_t uni = (size_t)E > (size_t)n * 32 ? (size_t)E : (size_t)n * 32;
    unsigned int* binned = (unsigned int*)(ws + o);
    float* h1s  = (float*)(ws + o);                    // overwrites binned after csr pass
    float* acc1 = (float*)(ws + o) + (size_t)n * F1;
    o += uni * 4;
    float* h2s = h1s;  // mm2 reads acc1, writes h2s (h1s dead after agg1)
    float* out = (float*)d_out;

    const int B = 256;
    int GA = (E + A_CHUNK - 1) / A_CHUNK;
    int gN = (n + B - 1) / B;

    hipMemsetAsync(bucket_cnt, 0, 512 * sizeof(int), stream);

    binhist_kernel<<<GA, B, 0, stream>>>(dst, bucket_cnt, E, NB);
    bucketscan_kernel<<<1, 512, 0, stream>>>(bucket_cnt, bucket_base, bucket_cursor, NB, E);
    bin_kernel<<<GA, B, 0, stream>>>(src, dst, bucket_cursor, binned, E, NB);
    csr_kernel<<<NB, B, 0, stream>>>(binned, bucket_base, row_ptr, row_end, dinv, adj, n);

    mm1_kernel<<<(n + NT - 1) / NT, B, 0, stream>>>(x, W1, dinv, h1s, n);

    agg1_kernel<<<((size_t)n * F1 + B - 1) / B, B, 0, stream>>>(row_ptr, row_end, adj, h1s, dinv, b1, acc1, n);

    mm2_kernel<<<gN, B, 0, stream>>>(acc1, W2, dinv, h2s, n);

    agg2_kernel<<<((size_t)n * 8 + B - 1) / B, B, 0, stream>>>(row_ptr, row_end, adj, h2s, dinv, b2, out, n);
}